// Round 5
// baseline (967.269 us; speedup 1.0000x reference)
//
#include <hip/hip_runtime.h>
#include <math.h>

#define RNK 10
#define NG  55          // packed lower-triangular 10x10
#define TPB 256
#define TPBU 64         // update block: 1 wave, VGPR cap lifted -> no Cholesky spill
#define GJ   64         // gram: j columns per block (4 waves x 16)
#define GWRD 4          // gram: mask words per thread (128 rows)
#define GROWS_B (4 * GWRD * 32)   // gram rows per block = 512 (4 subslabs)
#define P2RPT 64        // pass2: rows per thread
#define ROWS_P2 (4 * P2RPT)       // pass2 rows per block = 256 (4 subslabs)
#define ROWS_P 64       // pass1 rows per chunk (LDS-staged D)
#define ITILE 16        // rows per block in final GEMM

typedef float f2 __attribute__((ext_vector_type(2)));

__device__ __forceinline__ constexpr int tri(int a, int b) { return a*(a+1)/2 + b; }
// pair-accumulator base index per triangle row a (25 f2 pairs total)
constexpr int BASE2[10] = {0,0,1,2,4,6,9,12,16,20};

// sum across the 4 sub-lanes of each quad (lane = jo*4 + sub)
__device__ __forceinline__ float qsum(float v) {
    v += __shfl_xor(v, 1);
    v += __shfl_xor(v, 2);
    return v;
}

// ---------------- init ----------------
__global__ void init_kernel(const float* __restrict__ Uin, const float* __restrict__ Vin,
                            const float* __restrict__ cptr,
                            float* __restrict__ Ut, float* __restrict__ Vc,
                            float* __restrict__ Urow, float* __restrict__ Vrow,
                            float* __restrict__ Gbuf, float* __restrict__ tauacc,
                            float* __restrict__ rhs, float* __restrict__ alpha,
                            int m, int n, int qmax) {
    int idx = blockIdx.x * TPB + threadIdx.x;
    if (idx == 0) {
        float c  = *cptr;
        float A  = erff(c * 0.70710678118654752f);              // chi2_cdf(c^2, 1)
        float B  = c * 0.79788456080286536f * expf(-0.5f*c*c);
        *alpha = 0.5f*c*c*(1.0f - A) + 0.5f*(A - B);            // chi2_cdf(c^2,3)=A-B
    }
    if (idx < RNK * m) { int k = idx / m, i = idx - k*m; Ut[idx] = Uin[i*RNK + k]; }
    if (idx < RNK * m) Urow[idx] = Uin[idx];                    // same layout
    if (idx < RNK * n) Vc[idx] = Vin[idx];
    if (idx < RNK * n) { int j = idx / RNK, k = idx - j*RNK; Vrow[idx] = Vin[k*n + j]; }
    if (idx < (NG + 1) * qmax) Gbuf[idx] = 0.0f;
    if (idx < qmax) tauacc[idx] = 0.0f;
    if (idx < RNK * qmax) rhs[idx] = 0.0f;
}

// X [m,n] -> XT [n,m], 32x32 LDS tile
__global__ void transpose_kernel(const float* __restrict__ X, float* __restrict__ XT,
                                 int m, int n) {
    __shared__ float tile[32][33];
    int bx = blockIdx.x * 32, by = blockIdx.y * 32;
    int tx = threadIdx.x, ty = threadIdx.y;  // block (32,8)
    #pragma unroll
    for (int dy = 0; dy < 32; dy += 8)
        tile[ty+dy][tx] = X[(size_t)(by+ty+dy)*n + bx + tx];
    __syncthreads();
    #pragma unroll
    for (int dy = 0; dy < 32; dy += 8)
        XT[(size_t)(bx+ty+dy)*m + by + tx] = tile[tx][ty+dy];
}

// Build packed masks (see earlier rounds).
__global__ void mask_kernel(const float* __restrict__ X, unsigned* __restrict__ maskV,
                            unsigned* __restrict__ maskU, int m, int n) {
    int wave = threadIdx.x >> 6, lane = threadIdx.x & 63;
    int jbase = blockIdx.x * 256 + wave * 64;
    int j  = jbase + lane;
    int i0 = blockIdx.y * 32;
    unsigned wv = 0;
    for (int u = 0; u < 32; ++u) {
        float x = X[(size_t)(i0+u)*n + j];
        bool nz = (x != 0.0f);
        wv |= (nz ? 1u : 0u) << u;
        unsigned long long bb = __ballot(nz);
        if (lane == 0) {
            int jw = jbase >> 5;
            maskU[(size_t)jw     * m + (i0+u)] = (unsigned)bb;
            maskU[(size_t)(jw+1) * m + (i0+u)] = (unsigned)(bb >> 32);
        }
    }
    maskV[(size_t)blockIdx.y * n + j] = wv;
}

// ---------------- hubreg kernels ----------------
// Gram, atomic-traffic-minimized. R4 counters proved dur == atomic_bytes/BW
// (28.7 MB of device-scope fp32 RMWs -> memory fabric). New layout: wave =
// 16 j-columns x 4 row-subslabs (lane = jo*4+sub); each thread accumulates
// its 55+1 entries over 128 rows (4 mask words), then 2 shfl_xor rounds sum
// the quad and only sub==0 lanes issue atomics: 28.7 MB -> 7.2 MB.
// Block: 64 j x 512 rows, grid (q/64, p/512) = 512 blocks.
__global__ __launch_bounds__(TPB)
void gram_kernel(const unsigned* __restrict__ mask, const float* __restrict__ Drow,
                 float* __restrict__ Gbuf, int q, int p) {
    __shared__ __align__(16) float Dld[GROWS_B][12];   // 512 rows x 48 B = 24 KB
    int lane = threadIdx.x & 63, wave = threadIdx.x >> 6;
    int jo = lane >> 2, sub = lane & 3;
    int j  = blockIdx.x * GJ + wave * 16 + jo;
    int ib = blockIdx.y * GROWS_B;
    for (int t = threadIdx.x; t < GROWS_B * RNK; t += TPB) {   // 20 coalesced iters
        int row = t / RNK, k = t - row * RNK;
        Dld[row][k] = Drow[(size_t)ib * RNK + t];
    }
    __syncthreads();
    f2 acc2[25];                 // row a: pairs (b,b+1); even a leaves scalar b=a
    float accs[5];
    #pragma unroll
    for (int k = 0; k < 25; ++k) acc2[k] = (f2){0.0f, 0.0f};
    #pragma unroll
    for (int k = 0; k < 5; ++k) accs[k] = 0.0f;
    unsigned cnt = 0;
    int w0 = blockIdx.y * (4 * GWRD) + sub * GWRD;
    const float* dbase = &Dld[sub * (GWRD * 32)][0];
    unsigned wnext = mask[(size_t)w0 * q + j];
    for (int wi = 0; wi < GWRD; ++wi) {      // rolled: I-cache
        unsigned word = wnext;
        int wn = (wi + 1 < GWRD) ? (wi + 1) : (GWRD - 1);
        wnext = mask[(size_t)(w0 + wn) * q + j];   // hidden under the FMA block
        cnt += __popc(word);
        const float* drow = dbase + wi * (32 * 12);
        #pragma unroll
        for (int u = 0; u < 32; ++u) {       // fully unrolled: imm-offset ds_reads
            float f = (float)((word >> u) & 1u);
            f2 d2[5];
            #pragma unroll
            for (int k = 0; k < 5; ++k) d2[k] = *(const f2*)(drow + u * 12 + 2 * k);
            #pragma unroll
            for (int a = 0; a < RNK; ++a) {
                float da = d2[a >> 1][a & 1];
                float t  = f * da;
                f2 tv = {t, t};
                #pragma unroll
                for (int pb = 0; pb < (a + 1) / 2; ++pb)
                    acc2[BASE2[a] + pb] =
                        __builtin_elementwise_fma(tv, d2[pb], acc2[BASE2[a] + pb]);
                if ((a & 1) == 0) accs[a >> 1] = fmaf(t, da, accs[a >> 1]);
            }
        }
    }
    // quad reduction (all lanes participate -> no divergence before shfl)
    #pragma unroll
    for (int k = 0; k < 25; ++k) {
        acc2[k][0] = qsum(acc2[k][0]);
        acc2[k][1] = qsum(acc2[k][1]);
    }
    #pragma unroll
    for (int k = 0; k < 5; ++k) accs[k] = qsum(accs[k]);
    float fc = qsum((float)cnt);
    if (sub == 0) {
        #pragma unroll
        for (int a = 0; a < RNK; ++a) {
            #pragma unroll
            for (int pb = 0; pb < (a + 1) / 2; ++pb) {
                atomicAdd(&Gbuf[tri(a, 2*pb)   * q + j], acc2[BASE2[a] + pb][0]);
                atomicAdd(&Gbuf[tri(a, 2*pb+1) * q + j], acc2[BASE2[a] + pb][1]);
            }
            if ((a & 1) == 0) atomicAdd(&Gbuf[tri(a, a) * q + j], accs[a >> 1]);
        }
        atomicAdd(&Gbuf[NG * q + j], fc);
    }
}

// pass1: tauacc[j] += sum_i (clamp(resid, +-c*sig))^2. 1 col/thread, 8-deep Y
// prefetch, D chunk LDS-staged, dot via 5 v_pk_fma_f32. Atomics: 1/thread (1 MB,
// negligible) -> unchanged structure.
__global__ __launch_bounds__(TPB)
void pass1_kernel(const float* __restrict__ Y, const float* __restrict__ Drow,
                  const float* __restrict__ Bm, const float* __restrict__ sigstore,
                  const float* __restrict__ sigma0p, const float* __restrict__ cptr,
                  float* __restrict__ tauacc, int q, int p, int use_store) {
    __shared__ __align__(16) float Dp[ROWS_P][12];      // 64 rows x 48 B = 3 KB
    int j  = blockIdx.x * TPB + threadIdx.x;
    int i0 = blockIdx.y * ROWS_P;
    for (int t = threadIdx.x; t < ROWS_P * RNK; t += TPB) {
        int row = t / RNK, k = t - row * RNK;
        Dp[row][k] = Drow[(size_t)i0 * RNK + t];
    }
    __syncthreads();
    f2 b2[5];
    #pragma unroll
    for (int k = 0; k < 5; ++k)
        b2[k] = (f2){Bm[(2*k)*q + j], Bm[(2*k+1)*q + j]};
    float csg = (*cptr) * (use_store ? sigstore[j] : *sigma0p);
    float a0 = 0.0f;
    float y[8];
    #pragma unroll
    for (int u = 0; u < 8; ++u) y[u] = Y[(size_t)(i0+u)*q + j];
    for (int g = 0; g < ROWS_P; g += 8) {
        float yn[8];
        if (g + 8 < ROWS_P) {
            #pragma unroll
            for (int u = 0; u < 8; ++u) yn[u] = Y[(size_t)(i0+g+8+u)*q + j];
        } else {
            #pragma unroll
            for (int u = 0; u < 8; ++u) yn[u] = 0.0f;
        }
        #pragma unroll
        for (int u = 0; u < 8; ++u) {
            int rl = g + u;                   // block-local row
            f2 dot2 = {0.0f, 0.0f};
            #pragma unroll
            for (int k = 0; k < 5; ++k) {
                f2 d2 = *(const f2*)&Dp[rl][2*k];
                dot2 = __builtin_elementwise_fma(d2, b2[k], dot2);
            }
            float dot = dot2[0] + dot2[1];
            float r = (y[u] != 0.0f) ? y[u] - dot : 0.0f;
            r = fminf(fmaxf(r, -csg), csg);
            a0 = fmaf(r, r, a0);
        }
        #pragma unroll
        for (int u = 0; u < 8; ++u) y[u] = yn[u];
    }
    atomicAdd(&tauacc[j], a0);
}

// pass2: sigma_new inline from tauacc; rhs[k][j] += D[i,k]*clamp(resid,+-c*sigma_new).
// Same quad-subslab trick as gram: wave = 16 j x 4 subs, thread does 64 rows,
// shfl-reduce the 10 rhs accs, sub==0 lanes atomicAdd: 10.5 MB -> 2.6 MB.
// Block: 64 j x 256 rows, grid (q/64, p/256) = 1024 blocks.
__global__ __launch_bounds__(TPB)
void pass2_kernel(const float* __restrict__ Y, const float* __restrict__ Drow,
                  const float* __restrict__ Bm, const float* __restrict__ Gbuf,
                  const float* __restrict__ tauacc, float* __restrict__ sigstore,
                  const float* __restrict__ cptr, const float* __restrict__ alphap,
                  const float* __restrict__ lamdap, const float* __restrict__ sigma0p,
                  float* __restrict__ rhs, int q, int p, int mode) {
    __shared__ __align__(16) float Dp[ROWS_P2][12];     // 256 rows x 48 B = 12 KB
    int lane = threadIdx.x & 63, wave = threadIdx.x >> 6;
    int jo = lane >> 2, sub = lane & 3;
    int j  = blockIdx.x * GJ + wave * 16 + jo;
    int i0 = blockIdx.y * ROWS_P2;
    for (int t = threadIdx.x; t < ROWS_P2 * RNK; t += TPB) {
        int row = t / RNK, k = t - row * RNK;
        Dp[row][k] = Drow[(size_t)i0 * RNK + t];
    }
    __syncthreads();
    f2 b2[5];
    #pragma unroll
    for (int k = 0; k < 5; ++k)
        b2[k] = (f2){Bm[(2*k)*q + j], Bm[(2*k+1)*q + j]};
    float so  = mode ? sigstore[j] : *sigma0p;
    float nb  = Gbuf[NG*q + j];
    float tau = sqrtf(tauacc[j] / (2.0f * nb * (*alphap))) / so;
    float sg  = so * powf(tau, *lamdap);
    if (mode == 0 && blockIdx.y == 0 && sub == 0) sigstore[j] = sg;
    float csg = (*cptr) * sg;

    int ibase = i0 + sub * P2RPT;             // this thread's 64-row subslab
    const float* dbase = &Dp[sub * P2RPT][0];
    f2 a2[5];
    #pragma unroll
    for (int k = 0; k < 5; ++k) a2[k] = (f2){0.0f, 0.0f};
    float y[8];
    #pragma unroll
    for (int u = 0; u < 8; ++u) y[u] = Y[(size_t)(ibase+u)*q + j];
    for (int g = 0; g < P2RPT; g += 8) {
        float yn[8];
        if (g + 8 < P2RPT) {
            #pragma unroll
            for (int u = 0; u < 8; ++u) yn[u] = Y[(size_t)(ibase+g+8+u)*q + j];
        } else {
            #pragma unroll
            for (int u = 0; u < 8; ++u) yn[u] = 0.0f;
        }
        const float* drow = dbase + g * 12;
        #pragma unroll
        for (int u = 0; u < 8; ++u) {
            f2 d2[5];
            #pragma unroll
            for (int k = 0; k < 5; ++k) d2[k] = *(const f2*)(drow + u * 12 + 2 * k);
            f2 dot2 = {0.0f, 0.0f};
            #pragma unroll
            for (int k = 0; k < 5; ++k)
                dot2 = __builtin_elementwise_fma(d2[k], b2[k], dot2);
            float dot = dot2[0] + dot2[1];
            float r = (y[u] != 0.0f) ? y[u] - dot : 0.0f;
            r = fminf(fmaxf(r, -csg), csg);   // psi2 * sigma_new
            f2 rv = {r, r};
            #pragma unroll
            for (int k = 0; k < 5; ++k)
                a2[k] = __builtin_elementwise_fma(d2[k], rv, a2[k]);
        }
        #pragma unroll
        for (int u = 0; u < 8; ++u) y[u] = yn[u];
    }
    #pragma unroll
    for (int k = 0; k < 5; ++k) {
        a2[k][0] = qsum(a2[k][0]);
        a2[k][1] = qsum(a2[k][1]);
    }
    if (sub == 0) {
        #pragma unroll
        for (int k = 0; k < 5; ++k) {
            atomicAdd(&rhs[(2*k)*q   + j], a2[k][0]);
            atomicAdd(&rhs[(2*k+1)*q + j], a2[k][1]);
        }
    }
}

// Cholesky of raw G (in registers) + solve + beta += mu*delta.
// 64-thread blocks + launch_bounds(64): no scratch spill.
__global__ __launch_bounds__(TPBU)
void update_kernel(float* __restrict__ Gbuf, float* __restrict__ rhs,
                   float* __restrict__ Bm, float* __restrict__ Brow,
                   const float* __restrict__ mup,
                   float* __restrict__ tauacc, int q, int zero_g) {
    int j = blockIdx.x * TPBU + threadIdx.x;
    if (j >= q) return;
    float g[NG];
    #pragma unroll
    for (int k = 0; k < NG; ++k) g[k] = Gbuf[k*q + j];
    #pragma unroll
    for (int a = 0; a < RNK; ++a) {          // in-register Cholesky
        #pragma unroll
        for (int b = 0; b < a; ++b) {
            float s = g[tri(a,b)];
            #pragma unroll
            for (int k = 0; k < b; ++k) s -= g[tri(a,k)] * g[tri(b,k)];
            g[tri(a,b)] = s / g[tri(b,b)];
        }
        float s = g[tri(a,a)];
        #pragma unroll
        for (int k = 0; k < a; ++k) s -= g[tri(a,k)] * g[tri(a,k)];
        g[tri(a,a)] = sqrtf(s);
    }
    float x[RNK];
    #pragma unroll
    for (int k = 0; k < RNK; ++k) x[k] = rhs[k*q + j];
    #pragma unroll
    for (int a = 0; a < RNK; ++a) {          // forward: L y = rhs
        float s = x[a];
        #pragma unroll
        for (int k = 0; k < a; ++k) s -= g[tri(a,k)] * x[k];
        x[a] = s / g[tri(a,a)];
    }
    #pragma unroll
    for (int a = RNK-1; a >= 0; --a) {       // backward: L^T d = y
        float s = x[a];
        #pragma unroll
        for (int k = a+1; k < RNK; ++k) s -= g[tri(k,a)] * x[k];
        x[a] = s / g[tri(a,a)];
    }
    float mu = *mup;
    #pragma unroll
    for (int k = 0; k < RNK; ++k) {
        float nb = Bm[k*q + j] + mu * x[k];
        Bm[k*q + j] = nb;
        Brow[(size_t)j*RNK + k] = nb;
    }
    tauacc[j] = 0.0f;
    #pragma unroll
    for (int k = 0; k < RNK; ++k) rhs[k*q + j] = 0.0f;
    if (zero_g) {
        #pragma unroll
        for (int k = 0; k <= NG; ++k) Gbuf[k*q + j] = 0.0f;
    }
}

// final: out[i*n+j] = sum_k Ut[k*m+i] * Vc[k*n+j]
__global__ void gemm_kernel(const float* __restrict__ Ut, const float* __restrict__ Vc,
                            float* __restrict__ out, int m, int n) {
    int j  = blockIdx.x * TPB + threadIdx.x;
    int i0 = blockIdx.y * ITILE;
    float v[RNK];
    #pragma unroll
    for (int k = 0; k < RNK; ++k) v[k] = Vc[k*n + j];
    for (int i = i0; i < i0 + ITILE; ++i) {
        float acc = 0.0f;
        #pragma unroll
        for (int k = 0; k < RNK; ++k) acc = fmaf(Ut[k*m + i], v[k], acc);
        out[(size_t)i*n + j] = acc;
    }
}

// ---------------- host side ----------------

namespace {
struct Scratch {
    float *Ut, *Vc, *Urow, *Vrow, *Gbuf, *rhs, *sigma, *tauacc, *alpha;
    unsigned *maskV, *maskU;
};

static void hubreg(const float* Y, const unsigned* mask, const float* Drow,
                   float* Bm, float* Brow, int q, int p,
                   const float* c, const float* lamda, const float* mu, const float* sigma0,
                   const Scratch& s, hipStream_t stream) {
    dim3 gg(q / GJ, p / GROWS_B);        // gram: (64,8) = 512 blocks
    dim3 gp(q / TPB, p / ROWS_P);        // pass1: (16,64) = 1024 blocks
    dim3 gp2(q / GJ, p / ROWS_P2);       // pass2: (64,16) = 1024 blocks
    dim3 gj(q / TPBU);                   // update: 64 blocks of 1 wave

    gram_kernel  <<<gg, TPB, 0, stream>>>(mask, Drow, s.Gbuf, q, p);
    pass1_kernel <<<gp, TPB, 0, stream>>>(Y, Drow, Bm, s.sigma, sigma0, c, s.tauacc, q, p, 0);
    pass2_kernel <<<gp2, TPB, 0, stream>>>(Y, Drow, Bm, s.Gbuf, s.tauacc, s.sigma, c,
                                           s.alpha, lamda, sigma0, s.rhs, q, p, 0);
    update_kernel<<<gj, TPBU, 0, stream>>>(s.Gbuf, s.rhs, Bm, Brow, mu, s.tauacc, q, 0);
    pass1_kernel <<<gp, TPB, 0, stream>>>(Y, Drow, Bm, s.sigma, sigma0, c, s.tauacc, q, p, 1);
    pass2_kernel <<<gp2, TPB, 0, stream>>>(Y, Drow, Bm, s.Gbuf, s.tauacc, s.sigma, c,
                                           s.alpha, lamda, sigma0, s.rhs, q, p, 1);
    update_kernel<<<gj, TPBU, 0, stream>>>(s.Gbuf, s.rhs, Bm, Brow, mu, s.tauacc, q, 1);
}
} // namespace

extern "C" void kernel_launch(void* const* d_in, const int* in_sizes, int n_in,
                              void* d_out, int out_size, void* d_ws, size_t ws_size,
                              hipStream_t stream) {
    const float* Uin    = (const float*)d_in[0];
    const float* Vin    = (const float*)d_in[1];
    const float* X      = (const float*)d_in[2];
    const float* c      = (const float*)d_in[3];
    const float* lamda  = (const float*)d_in[4];
    const float* mu     = (const float*)d_in[5];
    const float* sigma0 = (const float*)d_in[6];
    float* out = (float*)d_out;

    const int m = in_sizes[0] / RNK;   // 4096
    const int n = in_sizes[1] / RNK;   // 4096
    const int qmax = (m > n) ? m : n;

    float* w = (float*)d_ws;
    auto align64 = [](size_t x) { return (x + 63) & ~(size_t)63; };
    size_t off = 0;
    Scratch s;
    s.Ut     = w + off; off = align64(off + (size_t)RNK * m);
    s.Vc     = w + off; off = align64(off + (size_t)RNK * n);
    s.Urow   = w + off; off = align64(off + (size_t)RNK * m);
    s.Vrow   = w + off; off = align64(off + (size_t)RNK * n);
    s.Gbuf   = w + off; off = align64(off + (size_t)(NG + 1) * qmax);
    s.rhs    = w + off; off = align64(off + (size_t)RNK * qmax);
    s.sigma  = w + off; off = align64(off + (size_t)qmax);
    s.tauacc = w + off; off = align64(off + (size_t)qmax);
    s.alpha  = w + off; off = align64(off + 64);
    s.maskV  = (unsigned*)(w + off); off = align64(off + (size_t)(m/32) * n);
    s.maskU  = (unsigned*)(w + off); off = align64(off + (size_t)(n/32) * m);
    (void)ws_size; (void)n_in; (void)out_size;

    {
        int tot = (NG + 1) * qmax;
        init_kernel<<<(tot + TPB - 1) / TPB, TPB, 0, stream>>>(
            Uin, Vin, c, s.Ut, s.Vc, s.Urow, s.Vrow, s.Gbuf, s.tauacc, s.rhs,
            s.alpha, m, n, qmax);
    }
    // X [m,n] -> XT [n,m] staged in d_out (dead until final GEMM overwrites it)
    transpose_kernel<<<dim3(n / 32, m / 32), dim3(32, 8), 0, stream>>>(X, out, m, n);
    mask_kernel<<<dim3(n / 256, m / 32), TPB, 0, stream>>>(X, s.maskV, s.maskU, m, n);

    for (int layer = 0; layer < 3; ++layer) {
        // V-step: q=n regressions (cols of X), D rows = U rows (Urow), beta = V cols
        hubreg(X,   s.maskV, s.Urow, s.Vc, s.Vrow, n, m, c, lamda, mu, sigma0, s, stream);
        // U-step: q=m regressions (rows of X), Y = XT, D rows = V cols (Vrow), beta = U rows
        hubreg(out, s.maskU, s.Vrow, s.Ut, s.Urow, m, n, c, lamda, mu, sigma0, s, stream);
    }

    gemm_kernel<<<dim3(n / TPB, m / ITILE), TPB, 0, stream>>>(s.Ut, s.Vc, out, m, n);
}

// Round 6
// 848.465 us; speedup vs baseline: 1.1400x; 1.1400x over previous
//
#include <hip/hip_runtime.h>
#include <math.h>

#define RNK 10
#define NG  55          // packed lower-triangular 10x10
#define TPB 256
#define TPBU 64         // update block: 1 wave, VGPR cap lifted -> no Cholesky spill
#define GJ   64         // gram: j columns per block (4 waves x 16)
#define GWRD 4          // gram: mask words per thread (128 rows)
#define GROWS_B (4 * GWRD * 32)   // gram rows per block = 512 (4 subslabs)
#define GSUBP (GWRD * 32 * 12 + 8) // subslab stride in floats (1544): banks 0/8/16/24
#define ROWS_P 64       // pass1/pass2 rows per chunk (LDS-staged D, broadcast reads)
#define ITILE 16        // rows per block in final GEMM

typedef float f2 __attribute__((ext_vector_type(2)));

__device__ __forceinline__ constexpr int tri(int a, int b) { return a*(a+1)/2 + b; }
// pair-accumulator base index per triangle row a (25 f2 pairs total)
constexpr int BASE2[10] = {0,0,1,2,4,6,9,12,16,20};

// sum across the 4 sub-lanes of each quad (lane = jo*4 + sub)
__device__ __forceinline__ float qsum(float v) {
    v += __shfl_xor(v, 1);
    v += __shfl_xor(v, 2);
    return v;
}

// ---------------- init ----------------
__global__ void init_kernel(const float* __restrict__ Uin, const float* __restrict__ Vin,
                            const float* __restrict__ cptr,
                            float* __restrict__ Ut, float* __restrict__ Vc,
                            float* __restrict__ Urow, float* __restrict__ Vrow,
                            float* __restrict__ Gbuf, float* __restrict__ tauacc,
                            float* __restrict__ rhs, float* __restrict__ alpha,
                            int m, int n, int qmax) {
    int idx = blockIdx.x * TPB + threadIdx.x;
    if (idx == 0) {
        float c  = *cptr;
        float A  = erff(c * 0.70710678118654752f);              // chi2_cdf(c^2, 1)
        float B  = c * 0.79788456080286536f * expf(-0.5f*c*c);
        *alpha = 0.5f*c*c*(1.0f - A) + 0.5f*(A - B);            // chi2_cdf(c^2,3)=A-B
    }
    if (idx < RNK * m) { int k = idx / m, i = idx - k*m; Ut[idx] = Uin[i*RNK + k]; }
    if (idx < RNK * m) Urow[idx] = Uin[idx];                    // same layout
    if (idx < RNK * n) Vc[idx] = Vin[idx];
    if (idx < RNK * n) { int j = idx / RNK, k = idx - j*RNK; Vrow[idx] = Vin[k*n + j]; }
    if (idx < (NG + 1) * qmax) Gbuf[idx] = 0.0f;
    if (idx < qmax) tauacc[idx] = 0.0f;
    if (idx < RNK * qmax) rhs[idx] = 0.0f;
}

// X [m,n] -> XT [n,m], 32x32 LDS tile.  FUSED: also emits both packed masks
// from the tile (kills mask_kernel's second 67 MB read of X).
// maskV [m/32][n]: bit u of word (w,j) = (X[32w+u, j] != 0)  -> ty==0 scans col.
// maskU [n/32][m]: bit u of word (w,i) = (X[i, 32w+u] != 0)  -> ty==1 scans row.
// tile stride 33 makes both scans bank-conflict-free ((u+tx)%32 distinct).
__global__ void transpose_kernel(const float* __restrict__ X, float* __restrict__ XT,
                                 unsigned* __restrict__ maskV, unsigned* __restrict__ maskU,
                                 int m, int n) {
    __shared__ float tile[32][33];
    int bx = blockIdx.x * 32, by = blockIdx.y * 32;
    int tx = threadIdx.x, ty = threadIdx.y;  // block (32,8)
    #pragma unroll
    for (int dy = 0; dy < 32; dy += 8)
        tile[ty+dy][tx] = X[(size_t)(by+ty+dy)*n + bx + tx];
    __syncthreads();
    #pragma unroll
    for (int dy = 0; dy < 32; dy += 8)
        XT[(size_t)(bx+ty+dy)*m + by + tx] = tile[tx][ty+dy];
    if (ty == 0) {                 // column j = bx+tx, rows by..by+31
        unsigned wv = 0;
        #pragma unroll
        for (int u = 0; u < 32; ++u)
            wv |= (tile[u][tx] != 0.0f ? 1u : 0u) << u;
        maskV[(size_t)blockIdx.y * n + bx + tx] = wv;
    } else if (ty == 1) {          // row i = by+tx, cols bx..bx+31
        unsigned wu = 0;
        #pragma unroll
        for (int u = 0; u < 32; ++u)
            wu |= (tile[tx][u] != 0.0f ? 1u : 0u) << u;
        maskU[(size_t)blockIdx.x * m + by + tx] = wu;
    }
}

// ---------------- hubreg kernels ----------------
// Gram, atomic-traffic-minimized (R5 win: dur == atomic_bytes/BW, 28.7->7.2 MB
// via quad-subslab + shfl reduction). R6 fix: subslab LDS stride padded
// 1536->1544 dwords so the 4 subs read banks 0/8/16/24 (was 4-way same-bank,
// SQ_LDS_BANK_CONFLICT=20480). Block: 64 j x 512 rows, grid (q/64, p/512).
__global__ __launch_bounds__(TPB)
void gram_kernel(const unsigned* __restrict__ mask, const float* __restrict__ Drow,
                 float* __restrict__ Gbuf, int q, int p) {
    __shared__ __align__(16) float Dld[4 * GSUBP];     // 4 subslabs x 1544 = 24.7 KB
    int lane = threadIdx.x & 63, wave = threadIdx.x >> 6;
    int jo = lane >> 2, sub = lane & 3;
    int j  = blockIdx.x * GJ + wave * 16 + jo;
    int ib = blockIdx.y * GROWS_B;
    for (int t = threadIdx.x; t < GROWS_B * RNK; t += TPB) {   // 20 coalesced iters
        int row = t / RNK, k = t - row * RNK;
        Dld[(row >> 7) * GSUBP + (row & 127) * 12 + k] = Drow[(size_t)ib * RNK + t];
    }
    __syncthreads();
    f2 acc2[25];                 // row a: pairs (b,b+1); even a leaves scalar b=a
    float accs[5];
    #pragma unroll
    for (int k = 0; k < 25; ++k) acc2[k] = (f2){0.0f, 0.0f};
    #pragma unroll
    for (int k = 0; k < 5; ++k) accs[k] = 0.0f;
    unsigned cnt = 0;
    int w0 = blockIdx.y * (4 * GWRD) + sub * GWRD;
    const float* dbase = Dld + sub * GSUBP;
    unsigned wnext = mask[(size_t)w0 * q + j];
    for (int wi = 0; wi < GWRD; ++wi) {      // rolled: I-cache
        unsigned word = wnext;
        int wn = (wi + 1 < GWRD) ? (wi + 1) : (GWRD - 1);
        wnext = mask[(size_t)(w0 + wn) * q + j];   // hidden under the FMA block
        cnt += __popc(word);
        const float* drow = dbase + wi * (32 * 12);
        #pragma unroll
        for (int u = 0; u < 32; ++u) {       // fully unrolled: imm-offset ds_reads
            float f = (float)((word >> u) & 1u);
            f2 d2[5];
            #pragma unroll
            for (int k = 0; k < 5; ++k) d2[k] = *(const f2*)(drow + u * 12 + 2 * k);
            #pragma unroll
            for (int a = 0; a < RNK; ++a) {
                float da = d2[a >> 1][a & 1];
                float t  = f * da;
                f2 tv = {t, t};
                #pragma unroll
                for (int pb = 0; pb < (a + 1) / 2; ++pb)
                    acc2[BASE2[a] + pb] =
                        __builtin_elementwise_fma(tv, d2[pb], acc2[BASE2[a] + pb]);
                if ((a & 1) == 0) accs[a >> 1] = fmaf(t, da, accs[a >> 1]);
            }
        }
    }
    // quad reduction (all lanes participate -> no divergence before shfl)
    #pragma unroll
    for (int k = 0; k < 25; ++k) {
        acc2[k][0] = qsum(acc2[k][0]);
        acc2[k][1] = qsum(acc2[k][1]);
    }
    #pragma unroll
    for (int k = 0; k < 5; ++k) accs[k] = qsum(accs[k]);
    float fc = qsum((float)cnt);
    if (sub == 0) {
        #pragma unroll
        for (int a = 0; a < RNK; ++a) {
            #pragma unroll
            for (int pb = 0; pb < (a + 1) / 2; ++pb) {
                atomicAdd(&Gbuf[tri(a, 2*pb)   * q + j], acc2[BASE2[a] + pb][0]);
                atomicAdd(&Gbuf[tri(a, 2*pb+1) * q + j], acc2[BASE2[a] + pb][1]);
            }
            if ((a & 1) == 0) atomicAdd(&Gbuf[tri(a, a) * q + j], accs[a >> 1]);
        }
        atomicAdd(&Gbuf[NG * q + j], fc);
    }
}

// pass1: tauacc[j] += sum_i (clamp(resid, +-c*sig))^2. 1 col/thread, 8-deep Y
// prefetch, D chunk LDS-staged (broadcast reads), dot via 5 v_pk_fma_f32.
__global__ __launch_bounds__(TPB)
void pass1_kernel(const float* __restrict__ Y, const float* __restrict__ Drow,
                  const float* __restrict__ Bm, const float* __restrict__ sigstore,
                  const float* __restrict__ sigma0p, const float* __restrict__ cptr,
                  float* __restrict__ tauacc, int q, int p, int use_store) {
    __shared__ __align__(16) float Dp[ROWS_P][12];      // 64 rows x 48 B = 3 KB
    int j  = blockIdx.x * TPB + threadIdx.x;
    int i0 = blockIdx.y * ROWS_P;
    for (int t = threadIdx.x; t < ROWS_P * RNK; t += TPB) {
        int row = t / RNK, k = t - row * RNK;
        Dp[row][k] = Drow[(size_t)i0 * RNK + t];
    }
    __syncthreads();
    f2 b2[5];
    #pragma unroll
    for (int k = 0; k < 5; ++k)
        b2[k] = (f2){Bm[(2*k)*q + j], Bm[(2*k+1)*q + j]};
    float csg = (*cptr) * (use_store ? sigstore[j] : *sigma0p);
    float a0 = 0.0f;
    float y[8];
    #pragma unroll
    for (int u = 0; u < 8; ++u) y[u] = Y[(size_t)(i0+u)*q + j];
    for (int g = 0; g < ROWS_P; g += 8) {
        float yn[8];
        if (g + 8 < ROWS_P) {
            #pragma unroll
            for (int u = 0; u < 8; ++u) yn[u] = Y[(size_t)(i0+g+8+u)*q + j];
        } else {
            #pragma unroll
            for (int u = 0; u < 8; ++u) yn[u] = 0.0f;
        }
        #pragma unroll
        for (int u = 0; u < 8; ++u) {
            int rl = g + u;                   // block-local row
            f2 dot2 = {0.0f, 0.0f};
            #pragma unroll
            for (int k = 0; k < 5; ++k) {
                f2 d2 = *(const f2*)&Dp[rl][2*k];
                dot2 = __builtin_elementwise_fma(d2, b2[k], dot2);
            }
            float dot = dot2[0] + dot2[1];
            float r = (y[u] != 0.0f) ? y[u] - dot : 0.0f;
            r = fminf(fmaxf(r, -csg), csg);
            a0 = fmaf(r, r, a0);
        }
        #pragma unroll
        for (int u = 0; u < 8; ++u) y[u] = yn[u];
    }
    atomicAdd(&tauacc[j], a0);
}

// pass2 (REVERTED to R4 broadcast structure -- R5's quad-subslab variant cost
// ~8-12us/dispatch: broke Y-load contiguity + broadcast D reads; atomic saving
// didn't pay on this Y-stream-bound kernel). sigma_new inline from tauacc;
// rhs[k][j] += D[i,k]*clamp(resid,+-c*sigma_new); 5 pk_fma accumulate.
__global__ __launch_bounds__(TPB)
void pass2_kernel(const float* __restrict__ Y, const float* __restrict__ Drow,
                  const float* __restrict__ Bm, const float* __restrict__ Gbuf,
                  const float* __restrict__ tauacc, float* __restrict__ sigstore,
                  const float* __restrict__ cptr, const float* __restrict__ alphap,
                  const float* __restrict__ lamdap, const float* __restrict__ sigma0p,
                  float* __restrict__ rhs, int q, int p, int mode) {
    __shared__ __align__(16) float Dp[ROWS_P][12];
    int j  = blockIdx.x * TPB + threadIdx.x;
    int i0 = blockIdx.y * ROWS_P;
    for (int t = threadIdx.x; t < ROWS_P * RNK; t += TPB) {
        int row = t / RNK, k = t - row * RNK;
        Dp[row][k] = Drow[(size_t)i0 * RNK + t];
    }
    __syncthreads();
    f2 b2[5];
    #pragma unroll
    for (int k = 0; k < 5; ++k)
        b2[k] = (f2){Bm[(2*k)*q + j], Bm[(2*k+1)*q + j]};
    float so  = mode ? sigstore[j] : *sigma0p;
    float nb  = Gbuf[NG*q + j];
    float tau = sqrtf(tauacc[j] / (2.0f * nb * (*alphap))) / so;
    float sg  = so * powf(tau, *lamdap);
    if (mode == 0 && blockIdx.y == 0) sigstore[j] = sg;
    float csg = (*cptr) * sg;

    f2 a2[5];
    #pragma unroll
    for (int k = 0; k < 5; ++k) a2[k] = (f2){0.0f, 0.0f};
    float y[8];
    #pragma unroll
    for (int u = 0; u < 8; ++u) y[u] = Y[(size_t)(i0+u)*q + j];
    for (int g = 0; g < ROWS_P; g += 8) {
        float yn[8];
        if (g + 8 < ROWS_P) {
            #pragma unroll
            for (int u = 0; u < 8; ++u) yn[u] = Y[(size_t)(i0+g+8+u)*q + j];
        } else {
            #pragma unroll
            for (int u = 0; u < 8; ++u) yn[u] = 0.0f;
        }
        #pragma unroll
        for (int u = 0; u < 8; ++u) {
            int rl = g + u;
            f2 d2[5];
            #pragma unroll
            for (int k = 0; k < 5; ++k) d2[k] = *(const f2*)&Dp[rl][2*k];
            f2 dot2 = {0.0f, 0.0f};
            #pragma unroll
            for (int k = 0; k < 5; ++k)
                dot2 = __builtin_elementwise_fma(d2[k], b2[k], dot2);
            float dot = dot2[0] + dot2[1];
            float r = (y[u] != 0.0f) ? y[u] - dot : 0.0f;
            r = fminf(fmaxf(r, -csg), csg);   // psi2 * sigma_new
            f2 rv = {r, r};
            #pragma unroll
            for (int k = 0; k < 5; ++k)
                a2[k] = __builtin_elementwise_fma(d2[k], rv, a2[k]);
        }
        #pragma unroll
        for (int u = 0; u < 8; ++u) y[u] = yn[u];
    }
    #pragma unroll
    for (int k = 0; k < 5; ++k) {
        atomicAdd(&rhs[(2*k)*q   + j], a2[k][0]);
        atomicAdd(&rhs[(2*k+1)*q + j], a2[k][1]);
    }
}

// Cholesky of raw G (in registers) + solve + beta += mu*delta.
// 64-thread blocks + launch_bounds(64): no scratch spill.
__global__ __launch_bounds__(TPBU)
void update_kernel(float* __restrict__ Gbuf, float* __restrict__ rhs,
                   float* __restrict__ Bm, float* __restrict__ Brow,
                   const float* __restrict__ mup,
                   float* __restrict__ tauacc, int q, int zero_g) {
    int j = blockIdx.x * TPBU + threadIdx.x;
    if (j >= q) return;
    float g[NG];
    #pragma unroll
    for (int k = 0; k < NG; ++k) g[k] = Gbuf[k*q + j];
    #pragma unroll
    for (int a = 0; a < RNK; ++a) {          // in-register Cholesky
        #pragma unroll
        for (int b = 0; b < a; ++b) {
            float s = g[tri(a,b)];
            #pragma unroll
            for (int k = 0; k < b; ++k) s -= g[tri(a,k)] * g[tri(b,k)];
            g[tri(a,b)] = s / g[tri(b,b)];
        }
        float s = g[tri(a,a)];
        #pragma unroll
        for (int k = 0; k < a; ++k) s -= g[tri(a,k)] * g[tri(a,k)];
        g[tri(a,a)] = sqrtf(s);
    }
    float x[RNK];
    #pragma unroll
    for (int k = 0; k < RNK; ++k) x[k] = rhs[k*q + j];
    #pragma unroll
    for (int a = 0; a < RNK; ++a) {          // forward: L y = rhs
        float s = x[a];
        #pragma unroll
        for (int k = 0; k < a; ++k) s -= g[tri(a,k)] * x[k];
        x[a] = s / g[tri(a,a)];
    }
    #pragma unroll
    for (int a = RNK-1; a >= 0; --a) {       // backward: L^T d = y
        float s = x[a];
        #pragma unroll
        for (int k = a+1; k < RNK; ++k) s -= g[tri(k,a)] * x[k];
        x[a] = s / g[tri(a,a)];
    }
    float mu = *mup;
    #pragma unroll
    for (int k = 0; k < RNK; ++k) {
        float nb = Bm[k*q + j] + mu * x[k];
        Bm[k*q + j] = nb;
        Brow[(size_t)j*RNK + k] = nb;
    }
    tauacc[j] = 0.0f;
    #pragma unroll
    for (int k = 0; k < RNK; ++k) rhs[k*q + j] = 0.0f;
    if (zero_g) {
        #pragma unroll
        for (int k = 0; k <= NG; ++k) Gbuf[k*q + j] = 0.0f;
    }
}

// final: out[i*n+j] = sum_k Ut[k*m+i] * Vc[k*n+j]
__global__ void gemm_kernel(const float* __restrict__ Ut, const float* __restrict__ Vc,
                            float* __restrict__ out, int m, int n) {
    int j  = blockIdx.x * TPB + threadIdx.x;
    int i0 = blockIdx.y * ITILE;
    float v[RNK];
    #pragma unroll
    for (int k = 0; k < RNK; ++k) v[k] = Vc[k*n + j];
    for (int i = i0; i < i0 + ITILE; ++i) {
        float acc = 0.0f;
        #pragma unroll
        for (int k = 0; k < RNK; ++k) acc = fmaf(Ut[k*m + i], v[k], acc);
        out[(size_t)i*n + j] = acc;
    }
}

// ---------------- host side ----------------

namespace {
struct Scratch {
    float *Ut, *Vc, *Urow, *Vrow, *Gbuf, *rhs, *sigma, *tauacc, *alpha;
    unsigned *maskV, *maskU;
};

static void hubreg(const float* Y, const unsigned* mask, const float* Drow,
                   float* Bm, float* Brow, int q, int p,
                   const float* c, const float* lamda, const float* mu, const float* sigma0,
                   const Scratch& s, hipStream_t stream) {
    dim3 gg(q / GJ, p / GROWS_B);        // gram: (64,8) = 512 blocks
    dim3 gp(q / TPB, p / ROWS_P);        // pass1/pass2: (16,64) = 1024 blocks
    dim3 gj(q / TPBU);                   // update: 64 blocks of 1 wave

    gram_kernel  <<<gg, TPB, 0, stream>>>(mask, Drow, s.Gbuf, q, p);
    pass1_kernel <<<gp, TPB, 0, stream>>>(Y, Drow, Bm, s.sigma, sigma0, c, s.tauacc, q, p, 0);
    pass2_kernel <<<gp, TPB, 0, stream>>>(Y, Drow, Bm, s.Gbuf, s.tauacc, s.sigma, c,
                                          s.alpha, lamda, sigma0, s.rhs, q, p, 0);
    update_kernel<<<gj, TPBU, 0, stream>>>(s.Gbuf, s.rhs, Bm, Brow, mu, s.tauacc, q, 0);
    pass1_kernel <<<gp, TPB, 0, stream>>>(Y, Drow, Bm, s.sigma, sigma0, c, s.tauacc, q, p, 1);
    pass2_kernel <<<gp, TPB, 0, stream>>>(Y, Drow, Bm, s.Gbuf, s.tauacc, s.sigma, c,
                                          s.alpha, lamda, sigma0, s.rhs, q, p, 1);
    update_kernel<<<gj, TPBU, 0, stream>>>(s.Gbuf, s.rhs, Bm, Brow, mu, s.tauacc, q, 1);
}
} // namespace

extern "C" void kernel_launch(void* const* d_in, const int* in_sizes, int n_in,
                              void* d_out, int out_size, void* d_ws, size_t ws_size,
                              hipStream_t stream) {
    const float* Uin    = (const float*)d_in[0];
    const float* Vin    = (const float*)d_in[1];
    const float* X      = (const float*)d_in[2];
    const float* c      = (const float*)d_in[3];
    const float* lamda  = (const float*)d_in[4];
    const float* mu     = (const float*)d_in[5];
    const float* sigma0 = (const float*)d_in[6];
    float* out = (float*)d_out;

    const int m = in_sizes[0] / RNK;   // 4096
    const int n = in_sizes[1] / RNK;   // 4096
    const int qmax = (m > n) ? m : n;

    float* w = (float*)d_ws;
    auto align64 = [](size_t x) { return (x + 63) & ~(size_t)63; };
    size_t off = 0;
    Scratch s;
    s.Ut     = w + off; off = align64(off + (size_t)RNK * m);
    s.Vc     = w + off; off = align64(off + (size_t)RNK * n);
    s.Urow   = w + off; off = align64(off + (size_t)RNK * m);
    s.Vrow   = w + off; off = align64(off + (size_t)RNK * n);
    s.Gbuf   = w + off; off = align64(off + (size_t)(NG + 1) * qmax);
    s.rhs    = w + off; off = align64(off + (size_t)RNK * qmax);
    s.sigma  = w + off; off = align64(off + (size_t)qmax);
    s.tauacc = w + off; off = align64(off + (size_t)qmax);
    s.alpha  = w + off; off = align64(off + 64);
    s.maskV  = (unsigned*)(w + off); off = align64(off + (size_t)(m/32) * n);
    s.maskU  = (unsigned*)(w + off); off = align64(off + (size_t)(n/32) * m);
    (void)ws_size; (void)n_in; (void)out_size;

    {
        int tot = (NG + 1) * qmax;
        init_kernel<<<(tot + TPB - 1) / TPB, TPB, 0, stream>>>(
            Uin, Vin, c, s.Ut, s.Vc, s.Urow, s.Vrow, s.Gbuf, s.tauacc, s.rhs,
            s.alpha, m, n, qmax);
    }
    // X [m,n] -> XT [n,m] staged in d_out (dead until final GEMM overwrites it);
    // fused mask emission (one X read total).
    transpose_kernel<<<dim3(n / 32, m / 32), dim3(32, 8), 0, stream>>>(
        X, out, s.maskV, s.maskU, m, n);

    for (int layer = 0; layer < 3; ++layer) {
        // V-step: q=n regressions (cols of X), D rows = U rows (Urow), beta = V cols
        hubreg(X,   s.maskV, s.Urow, s.Vc, s.Vrow, n, m, c, lamda, mu, sigma0, s, stream);
        // U-step: q=m regressions (rows of X), Y = XT, D rows = V cols (Vrow), beta = U rows
        hubreg(out, s.maskU, s.Vrow, s.Ut, s.Urow, m, n, c, lamda, mu, sigma0, s, stream);
    }

    gemm_kernel<<<dim3(n / TPB, m / ITILE), TPB, 0, stream>>>(s.Ut, s.Vc, out, m, n);
}